// Round 1
// baseline (81.873 us; speedup 1.0000x reference)
//
#include <hip/hip_runtime.h>
#include <math.h>

// SSIM char-matcher: img (1,1,1024,768) f32, chars (95,1,16,6) f32 -> argmax idx [64][128] int32
// H=16, W=6, WIN=3, tiles T=8192 (64 rows x 128 cols), refs R=95 (padded to 96)

static constexpr float kC1 = 1.0e-4f;   // 0.01^2
static constexpr float kC2 = 9.0e-4f;   // 0.03^2

struct KF { float k[9]; };

__device__ __forceinline__ int refl(int x, int n) {
  // x in [-1, n]; numpy 'reflect' (no edge repeat): -1 -> 1, n -> n-2
  if (x < 0) return -x;
  if (x >= n) return 2 * n - 2 - x;
  return x;
}

// ---------------- Kernel 1: per-ref precompute ----------------
// refdata layout: [hw(96)][12][96 r]; rows 0..8 = kflat[k]*Rp[k], 9 = mu_r,
// 10 = mu_r^2 + C1, 11 = sig_r + C2.  r = 95 is padding (finite, never argmax'd).
__global__ __launch_bounds__(128) void refprep_kernel(
    const float* __restrict__ chars, float* __restrict__ refdata,
    float* __restrict__ densR, KF kf) {
  const int hw = blockIdx.x;   // 0..95
  const int r = threadIdx.x;   // 0..127
  if (r >= 96) return;
  const int h = hw / 6, w = hw % 6;
  if (r < 95) {
    const float* cb = chars + r * 96;
    float wrv[9];
    float mu = 0.f, ex2 = 0.f;
#pragma unroll
    for (int i = 0; i < 3; ++i) {
      const int hh = refl(h + i - 1, 16);
#pragma unroll
      for (int j = 0; j < 3; ++j) {
        const int ww = refl(w + j - 1, 6);
        const float p = cb[hh * 6 + ww];
        const float kv = kf.k[i * 3 + j];
        wrv[i * 3 + j] = kv * p;
        mu += kv * p;
        ex2 += kv * p * p;
      }
    }
    const float sig = ex2 - mu * mu;
#pragma unroll
    for (int k = 0; k < 9; ++k) refdata[(hw * 12 + k) * 96 + r] = wrv[k];
    refdata[(hw * 12 + 9) * 96 + r]  = mu;
    refdata[(hw * 12 + 10) * 96 + r] = mu * mu + kC1;
    refdata[(hw * 12 + 11) * 96 + r] = sig + kC2;
  } else {
#pragma unroll
    for (int k = 0; k < 9; ++k) refdata[(hw * 12 + k) * 96 + r] = 0.f;
    refdata[(hw * 12 + 9) * 96 + r]  = 0.f;
    refdata[(hw * 12 + 10) * 96 + r] = kC1;
    refdata[(hw * 12 + 11) * 96 + r] = kC2;
  }
  if (hw == 0) {
    if (r < 95) {
      float s = 0.f;
      for (int i = 0; i < 96; ++i) s += chars[r * 96 + i];
      densR[r] = s * (1.0f / 96.0f);
    } else {
      densR[r] = 0.f;
    }
  }
}

// ---------------- Kernel 2: main SSIM + argmax ----------------
// Block: 32 tiles x 96 refs, 512 threads = 4 hw-groups x (8 tile-thr x 16 ref-thr).
// Per-thread register tile: 4 tiles x 6 refs.
union SharedU {
  struct {
    float padT[4608];    // [pixel c(0..143)][tile(0..31)]  transposed, reflect-padded 18x8
    float statT[9216];   // [arr(0..2)][hw(0..95)][tile(0..31)]: 2*mu_t, mu_t^2, sig_t
  } live;
  float sb[12288];       // [group(4)][tile(32)][ref(96)] partial scores (reuses dead space)
};

__global__ __launch_bounds__(512, 2) void ssim_main_kernel(
    const float* __restrict__ img, const float* __restrict__ refdata,
    const float* __restrict__ densR, int* __restrict__ out, KF kf) {
  __shared__ SharedU u;
  __shared__ float refbuf[4][1152];  // per-group current-pixel ref chunk [12][96]
  __shared__ float densT[32];

  const int tid = threadIdx.x;
  const int g = tid >> 7;          // hw-group 0..3
  const int gtid = tid & 127;
  const int tthr = gtid >> 4;      // 0..7  -> 4 tiles each
  const int rthr = gtid & 15;      // 0..15 -> 6 refs each
  const int tl0 = tthr * 4;
  const int r0 = rthr * 6;
  const int blk = blockIdx.x;
  const int row0 = blk >> 2;           // tile-row 0..63
  const int c0 = (blk & 3) * 32;       // tile-col base

  // Phase A: stage reflect-padded tiles, transposed: padT[c][tl]
  for (int idx = tid; idx < 4608; idx += 512) {
    const int c = idx >> 5, tl = idx & 31;
    const int ph = c >> 3, pw = c & 7;
    const int h = refl(ph - 1, 16), w = refl(pw - 1, 6);
    u.live.padT[idx] = img[(row0 * 16 + h) * 768 + (c0 + tl) * 6 + w];
  }
  __syncthreads();

  // Tile densities (interior pixels only)
  if (tid < 32) {
    float s = 0.f;
    for (int h = 0; h < 16; ++h)
      for (int w = 0; w < 6; ++w)
        s += u.live.padT[((h + 1) * 8 + (w + 1)) * 32 + tid];
    densT[tid] = s * (1.0f / 96.0f);
  }
  // Phase B: per-(hw, tile) stats
  for (int idx = tid; idx < 3072; idx += 512) {
    const int hw = idx >> 5, tl = idx & 31;
    const int h = hw / 6, w = hw % 6;
    float mu = 0.f, ex2 = 0.f;
#pragma unroll
    for (int i = 0; i < 3; ++i)
#pragma unroll
      for (int j = 0; j < 3; ++j) {
        const float p = u.live.padT[((h + i) * 8 + (w + j)) * 32 + tl];
        const float kv = kf.k[i * 3 + j];
        mu += kv * p;
        ex2 += kv * p * p;
      }
    const float sig = ex2 - mu * mu;
    u.live.statT[(0 * 96 + hw) * 32 + tl] = 2.0f * mu;
    u.live.statT[(1 * 96 + hw) * 32 + tl] = mu * mu;
    u.live.statT[(2 * 96 + hw) * 32 + tl] = sig;
  }
  __syncthreads();

  const int hwBase = g * 24;
  // Prologue: stage first ref chunk for this group
  {
    const float* src = refdata + hwBase * 1152;
    const float4 a = *(const float4*)(src + gtid * 4);
    const float4 b = *(const float4*)(src + 512 + gtid * 4);
    const float cc = src[1024 + gtid];
    *(float4*)&refbuf[g][gtid * 4] = a;
    *(float4*)&refbuf[g][512 + gtid * 4] = b;
    refbuf[g][1024 + gtid] = cc;
  }
  __syncthreads();

  float score[4][6];
#pragma unroll
  for (int i = 0; i < 4; ++i)
#pragma unroll
    for (int j = 0; j < 6; ++j) score[i][j] = 0.f;

  for (int it = 0; it < 24; ++it) {
    const int hw = hwBase + it;
    // Prefetch next pixel's ref chunk into registers (hides global latency)
    float4 pa, pb; float pc;
    if (it < 23) {
      const float* src = refdata + (hw + 1) * 1152;
      pa = *(const float4*)(src + gtid * 4);
      pb = *(const float4*)(src + 512 + gtid * 4);
      pc = src[1024 + gtid];
    }
    const int h = hw / 6, w = hw % 6;
    const int pbase = (h * 8 + w) * 32 + tl0;
    const float* rb = refbuf[g];

    float4 v;
    v = *(const float4*)&u.live.statT[(0 * 96 + hw) * 32 + tl0];
    const float twomt[4] = {v.x, v.y, v.z, v.w};
    v = *(const float4*)&u.live.statT[(1 * 96 + hw) * 32 + tl0];
    const float mt2[4] = {v.x, v.y, v.z, v.w};
    v = *(const float4*)&u.live.statT[(2 * 96 + hw) * 32 + tl0];
    const float sigt[4] = {v.x, v.y, v.z, v.w};

    float mr[6], m2c[6], sgc[6];
#pragma unroll
    for (int jj = 0; jj < 3; ++jj) {
      float2 t;
      t = *(const float2*)&rb[9 * 96 + r0 + jj * 2];  mr[jj*2] = t.x;  mr[jj*2+1] = t.y;
      t = *(const float2*)&rb[10 * 96 + r0 + jj * 2]; m2c[jj*2] = t.x; m2c[jj*2+1] = t.y;
      t = *(const float2*)&rb[11 * 96 + r0 + jj * 2]; sgc[jj*2] = t.x; sgc[jj*2+1] = t.y;
    }

    float exr[4][6];
#pragma unroll
    for (int i = 0; i < 4; ++i)
#pragma unroll
      for (int j = 0; j < 6; ++j) exr[i][j] = 0.f;

#pragma unroll
    for (int ik = 0; ik < 3; ++ik)
#pragma unroll
      for (int jk = 0; jk < 3; ++jk) {
        const int k = ik * 3 + jk;
        const float4 tp4 = *(const float4*)&u.live.padT[pbase + (ik * 8 + jk) * 32];
        const float tp[4] = {tp4.x, tp4.y, tp4.z, tp4.w};
        float wr[6];
#pragma unroll
        for (int jj = 0; jj < 3; ++jj) {
          const float2 t = *(const float2*)&rb[k * 96 + r0 + jj * 2];
          wr[jj*2] = t.x; wr[jj*2+1] = t.y;
        }
#pragma unroll
        for (int i = 0; i < 4; ++i)
#pragma unroll
          for (int j = 0; j < 6; ++j)
            exr[i][j] = fmaf(tp[i], wr[j], exr[i][j]);
      }

#pragma unroll
    for (int i = 0; i < 4; ++i)
#pragma unroll
      for (int j = 0; j < 6; ++j) {
        const float am = twomt[i] * mr[j];
        const float n1 = am + kC1;
        const float n2 = fmaf(exr[i][j], 2.0f, kC2) - am;
        const float d1 = mt2[i] + m2c[j];
        const float d2 = sigt[i] + sgc[j];
        score[i][j] += (n1 * n2) / (d1 * d2);   // exact IEEE div: argmax safety
      }

    __syncthreads();
    if (it < 23) {
      *(float4*)&refbuf[g][gtid * 4] = pa;
      *(float4*)&refbuf[g][512 + gtid * 4] = pb;
      refbuf[g][1024 + gtid] = pc;
    }
    __syncthreads();
  }

  // Phase D: partial scores -> LDS (padT/statT now dead), deterministic sum + argmax
#pragma unroll
  for (int i = 0; i < 4; ++i)
#pragma unroll
    for (int j = 0; j < 6; ++j)
      u.sb[(g * 32 + tl0 + i) * 96 + r0 + j] = score[i][j];
  __syncthreads();

  if (tid < 32) {
    const float dt = densT[tid];
    float best = -1e30f; int bi = 0;
    for (int r = 0; r < 95; ++r) {
      float s = u.sb[(0 * 32 + tid) * 96 + r] + u.sb[(1 * 32 + tid) * 96 + r]
              + u.sb[(2 * 32 + tid) * 96 + r] + u.sb[(3 * 32 + tid) * 96 + r];
      s = s * (1.0f / 96.0f) - 3.0f * fabsf(dt - densR[r]);
      if (s > best) { best = s; bi = r; }   // strict >: first max, matches jnp.argmax
    }
    out[row0 * 128 + c0 + tid] = bi;
  }
}

// ---------------- Host launch ----------------
extern "C" void kernel_launch(void* const* d_in, const int* in_sizes, int n_in,
                              void* d_out, int out_size, void* d_ws, size_t ws_size,
                              hipStream_t stream) {
  (void)in_sizes; (void)n_in; (void)out_size; (void)ws_size;
  const float* img = (const float*)d_in[0];
  const float* chars = (const float*)d_in[1];
  int* out = (int*)d_out;
  float* refdata = (float*)d_ws;               // 96*12*96 floats = 442 KB
  float* densR = refdata + 96 * 12 * 96;       // +96 floats

  // Gaussian 3x3 kernel, computed exactly like the reference (f32 ops)
  KF kf;
  {
    float gg[3], s = 0.f;
    for (int i = 0; i < 3; ++i) {
      const float c = (float)i - 1.0f;
      gg[i] = expf(-(c * c) / (2.0f * 1.5f * 1.5f));
      s += gg[i];
    }
    float gn[3];
    for (int i = 0; i < 3; ++i) gn[i] = gg[i] / s;
    float k2[9]; float ks = 0.f;
    for (int i = 0; i < 3; ++i)
      for (int j = 0; j < 3; ++j) { k2[i * 3 + j] = gn[i] * gn[j]; ks += k2[i * 3 + j]; }
    for (int k = 0; k < 9; ++k) kf.k[k] = k2[k] / ks;
  }

  hipLaunchKernelGGL(refprep_kernel, dim3(96), dim3(128), 0, stream,
                     chars, refdata, densR, kf);
  hipLaunchKernelGGL(ssim_main_kernel, dim3(256), dim3(512), 0, stream,
                     img, refdata, densR, out, kf);
}

// Round 2
// 50.523 us; speedup vs baseline: 1.6205x; 1.6205x over previous
//
#include <hip/hip_runtime.h>
#include <math.h>

// SSIM char-matcher: img (1,1,1024,768) f32, chars (95,1,16,6) f32 -> argmax idx [64][128] int32
// H=16, W=6, WIN=3, tiles T=8192 (64 rows x 128 cols), refs R=95 (padded to 96)

static constexpr float kC1 = 1.0e-4f;   // 0.01^2
static constexpr float kC2 = 9.0e-4f;   // 0.03^2

struct KF { float k[9]; };

__device__ __forceinline__ int refl(int x, int n) {
  if (x < 0) return -x;
  if (x >= n) return 2 * n - 2 - x;
  return x;
}

// ---------------- Kernel 1: per-ref precompute ----------------
// refdata layout: [hw(96)][12][96 r]; rows 0..8 = kflat[k]*Rp[k], 9 = mu_r,
// 10 = mu_r^2 + C1, 11 = sig_r + C2.  r = 95 is padding (never argmax'd).
__global__ __launch_bounds__(128) void refprep_kernel(
    const float* __restrict__ chars, float* __restrict__ refdata,
    float* __restrict__ densR, KF kf) {
  const int hw = blockIdx.x;   // 0..95
  const int r = threadIdx.x;   // 0..127
  if (r >= 96) return;
  const int h = hw / 6, w = hw % 6;
  if (r < 95) {
    const float* cb = chars + r * 96;
    float wrv[9];
    float mu = 0.f, ex2 = 0.f;
#pragma unroll
    for (int i = 0; i < 3; ++i) {
      const int hh = refl(h + i - 1, 16);
#pragma unroll
      for (int j = 0; j < 3; ++j) {
        const int ww = refl(w + j - 1, 6);
        const float p = cb[hh * 6 + ww];
        const float kv = kf.k[i * 3 + j];
        wrv[i * 3 + j] = kv * p;
        mu += kv * p;
        ex2 += kv * p * p;
      }
    }
    const float sig = ex2 - mu * mu;
#pragma unroll
    for (int k = 0; k < 9; ++k) refdata[(hw * 12 + k) * 96 + r] = wrv[k];
    refdata[(hw * 12 + 9) * 96 + r]  = mu;
    refdata[(hw * 12 + 10) * 96 + r] = mu * mu + kC1;
    refdata[(hw * 12 + 11) * 96 + r] = sig + kC2;
  } else {
#pragma unroll
    for (int k = 0; k < 9; ++k) refdata[(hw * 12 + k) * 96 + r] = 0.f;
    refdata[(hw * 12 + 9) * 96 + r]  = 0.f;
    refdata[(hw * 12 + 10) * 96 + r] = kC1;
    refdata[(hw * 12 + 11) * 96 + r] = kC2;
  }
  if (hw == 0) {
    if (r < 95) {
      float s = 0.f;
      for (int i = 0; i < 96; ++i) s += chars[r * 96 + i];
      densR[r] = s * (1.0f / 96.0f);
    } else {
      densR[r] = 0.f;
    }
  }
}

// ---- async global->LDS staging of one 1152-float ref chunk (per wave) ----
// 4 x (64 lanes x 16B) + 2 x (64 lanes x 4B) = 4608 B. LDS dst is wave-uniform
// base; HW writes base + lane*size. Counts 6 on vmcnt.
__device__ __forceinline__ void stage_px(const float* __restrict__ src,
                                         float* dst, int lane) {
  const uintptr_t gs = (uintptr_t)src;
  const uintptr_t ls = (uintptr_t)dst;   // flat->AS3: low 32 bits are the LDS offset
#define G_(off) ((const __attribute__((address_space(1))) void*)(gs + (off)))
#define L_(off) ((__attribute__((address_space(3))) void*)(uint32_t)(ls + (off)))
  __builtin_amdgcn_global_load_lds(G_(0    + lane * 16), L_(0),    16, 0, 0);
  __builtin_amdgcn_global_load_lds(G_(1024 + lane * 16), L_(1024), 16, 0, 0);
  __builtin_amdgcn_global_load_lds(G_(2048 + lane * 16), L_(2048), 16, 0, 0);
  __builtin_amdgcn_global_load_lds(G_(3072 + lane * 16), L_(3072), 16, 0, 0);
  __builtin_amdgcn_global_load_lds(G_(4096 + lane * 4),  L_(4096), 4, 0, 0);
  __builtin_amdgcn_global_load_lds(G_(4352 + lane * 4),  L_(4352), 4, 0, 0);
#undef G_
#undef L_
}

// ---------------- Kernel 2: main SSIM + argmax ----------------
// 256 blocks x 512 threads. Block = 32 tiles x 96 refs (pad 95->96), 96 px.
// Wave w (8 waves) owns px range [12w, 12w+12), covers ALL 32x96 elements:
// lane = 4 tile-thr (8 tiles each) x 16 ref-thr (6 refs each) = 48 el/thread.
// Wave-private double-buffered ref chunk -> zero barriers in the main loop.
// Scores kept as running fractions (num,den); one exact div at the end.
__global__ __launch_bounds__(512, 2) void ssim_main_kernel(
    const float* __restrict__ img, const float* __restrict__ refdata,
    const float* __restrict__ densR, int* __restrict__ out, KF kf) {
  // smem map: [0..4608) padT  [4608..13824) statT  [13824..32256) refbuf(8 waves x 2 x 1152)
  // overlay after main loop: sb[8][32][97] = 24832 floats from offset 0.
  __shared__ float smem[32256];
  __shared__ float densT[32];
  float* padT = smem;
  float* statT = smem + 4608;

  const int tid = threadIdx.x;
  const int w = tid >> 6;          // wave 0..7
  const int lane = tid & 63;
  const int tthr = lane >> 4;      // 0..3  -> 8 tiles each
  const int rthr = lane & 15;      // 0..15 -> 6 refs each
  const int tl0 = tthr * 8;
  const int r0 = rthr * 6;
  const int blk = blockIdx.x;
  const int row0 = blk >> 2;           // tile-row 0..63
  const int c0 = (blk & 3) * 32;       // tile-col base
  const int hwBase = w * 12;
  float* rbuf = smem + 13824 + w * 2304;   // wave-private 2 x 1152

  // Issue px0 staging immediately (latency hides under phases A/B).
  stage_px(refdata + (size_t)hwBase * 1152, rbuf, lane);

  // Phase A: stage reflect-padded tiles, transposed: padT[c(0..143)][tile(0..31)]
  for (int idx = tid; idx < 4608; idx += 512) {
    const int c = idx >> 5, tl = idx & 31;
    const int ph = c >> 3, pw = c & 7;
    const int h = refl(ph - 1, 16), ww = refl(pw - 1, 6);
    padT[idx] = img[(row0 * 16 + h) * 768 + (c0 + tl) * 6 + ww];
  }
  __syncthreads();

  // Tile densities (interior pixels only)
  if (tid < 32) {
    float s = 0.f;
    for (int h = 0; h < 16; ++h)
      for (int ww = 0; ww < 6; ++ww)
        s += padT[((h + 1) * 8 + (ww + 1)) * 32 + tid];
    densT[tid] = s * (1.0f / 96.0f);
  }
  // Phase B: per-(hw, tile) stats: 2*mu_t, mu_t^2, sig_t
  for (int idx = tid; idx < 3072; idx += 512) {
    const int hw = idx >> 5, tl = idx & 31;
    const int h = hw / 6, ww = hw % 6;
    float mu = 0.f, ex2 = 0.f;
#pragma unroll
    for (int i = 0; i < 3; ++i)
#pragma unroll
      for (int j = 0; j < 3; ++j) {
        const float p = padT[((h + i) * 8 + (ww + j)) * 32 + tl];
        const float kv = kf.k[i * 3 + j];
        mu += kv * p;
        ex2 += kv * p * p;
      }
    const float sig = ex2 - mu * mu;
    statT[(0 * 96 + hw) * 32 + tl] = 2.0f * mu;
    statT[(1 * 96 + hw) * 32 + tl] = mu * mu;
    statT[(2 * 96 + hw) * 32 + tl] = sig;
  }
  __syncthreads();

  // Running fractions per element: score = num/den (div deferred to the end).
  float num[8][6], den[8][6];
#pragma unroll
  for (int i = 0; i < 8; ++i)
#pragma unroll
    for (int j = 0; j < 6; ++j) { num[i][j] = 0.f; den[i][j] = 1.f; }

#pragma unroll 1
  for (int it = 0; it < 12; ++it) {
    const int hw = hwBase + it;
    const float* buf = rbuf + (it & 1) * 1152;

    if (it < 11) {
      // Dst buffer's previous reads are long consumed; drain lgkm then issue.
      asm volatile("s_waitcnt lgkmcnt(0)" ::: "memory");
      stage_px(refdata + (size_t)(hw + 1) * 1152, rbuf + ((it + 1) & 1) * 1152, lane);
      asm volatile("s_waitcnt vmcnt(6)" ::: "memory");   // current chunk ready, next in flight
    } else {
      asm volatile("s_waitcnt vmcnt(0)" ::: "memory");
    }

    const int h6 = hw / 6, w6 = hw - h6 * 6;
    const int pb = (h6 * 8 + w6) * 32 + tl0;

    // exr[i][j] = sum_k Tp[k][tile_i] * (kflat[k]*Rp[k][ref_j])
    float exr[8][6];
#pragma unroll
    for (int i = 0; i < 8; ++i)
#pragma unroll
      for (int j = 0; j < 6; ++j) exr[i][j] = 0.f;

#pragma unroll
    for (int ik = 0; ik < 3; ++ik)
#pragma unroll
      for (int jk = 0; jk < 3; ++jk) {
        const int kk = ik * 3 + jk;
        const float4 t0 = *(const float4*)&padT[pb + (ik * 8 + jk) * 32];
        const float4 t1 = *(const float4*)&padT[pb + (ik * 8 + jk) * 32 + 4];
        const float tp[8] = {t0.x, t0.y, t0.z, t0.w, t1.x, t1.y, t1.z, t1.w};
        float wr[6];
#pragma unroll
        for (int jj = 0; jj < 3; ++jj) {
          const float2 t = *(const float2*)&buf[kk * 96 + r0 + jj * 2];
          wr[jj * 2] = t.x; wr[jj * 2 + 1] = t.y;
        }
#pragma unroll
        for (int i = 0; i < 8; ++i)
#pragma unroll
          for (int j = 0; j < 6; ++j)
            exr[i][j] = fmaf(tp[i], wr[j], exr[i][j]);
      }

    // tile stats (8 tiles)
    float twomt[8], mt2[8], sigt[8];
    {
      const int sb0 = hw * 32 + tl0;
      float4 v;
      v = *(const float4*)&statT[sb0];            twomt[0]=v.x; twomt[1]=v.y; twomt[2]=v.z; twomt[3]=v.w;
      v = *(const float4*)&statT[sb0 + 4];        twomt[4]=v.x; twomt[5]=v.y; twomt[6]=v.z; twomt[7]=v.w;
      v = *(const float4*)&statT[3072 + sb0];     mt2[0]=v.x; mt2[1]=v.y; mt2[2]=v.z; mt2[3]=v.w;
      v = *(const float4*)&statT[3072 + sb0 + 4]; mt2[4]=v.x; mt2[5]=v.y; mt2[6]=v.z; mt2[7]=v.w;
      v = *(const float4*)&statT[6144 + sb0];     sigt[0]=v.x; sigt[1]=v.y; sigt[2]=v.z; sigt[3]=v.w;
      v = *(const float4*)&statT[6144 + sb0 + 4]; sigt[4]=v.x; sigt[5]=v.y; sigt[6]=v.z; sigt[7]=v.w;
    }
    // ref stats (6 refs)
    float mr[6], m2c[6], sgc[6];
#pragma unroll
    for (int jj = 0; jj < 3; ++jj) {
      float2 t;
      t = *(const float2*)&buf[864 + r0 + jj * 2];  mr[jj*2] = t.x;  mr[jj*2+1] = t.y;
      t = *(const float2*)&buf[960 + r0 + jj * 2];  m2c[jj*2] = t.x; m2c[jj*2+1] = t.y;
      t = *(const float2*)&buf[1056 + r0 + jj * 2]; sgc[jj*2] = t.x; sgc[jj*2+1] = t.y;
    }

#pragma unroll
    for (int i = 0; i < 8; ++i)
#pragma unroll
      for (int j = 0; j < 6; ++j) {
        const float am = twomt[i] * mr[j];
        const float n1 = am + kC1;
        const float n2 = fmaf(exr[i][j], 2.0f, kC2) - am;
        const float d1 = mt2[i] + m2c[j];
        const float d2 = sigt[i] + sgc[j];
        const float nn = n1 * n2;
        const float dd = d1 * d2;
        num[i][j] = fmaf(nn, den[i][j], num[i][j] * dd);
        den[i][j] *= dd;
      }

    if (it == 3 || it == 7) {
      // Rescale: multiplying num & den by the SAME factor is exact for the
      // ratio; keeps den ~1 so products never underflow. rcp approx is fine.
#pragma unroll
      for (int i = 0; i < 8; ++i)
#pragma unroll
        for (int j = 0; j < 6; ++j) {
          const float s = __builtin_amdgcn_rcpf(den[i][j]);
          num[i][j] *= s;
          den[i][j] *= s;
        }
    }
  }

  // All waves done with padT/statT/refbuf -> overlay sb[8][32][97]
  __syncthreads();
  float* sbuf = smem;
#pragma unroll
  for (int i = 0; i < 8; ++i)
#pragma unroll
    for (int j = 0; j < 6; ++j)
      sbuf[(w * 32 + tl0 + i) * 97 + r0 + j] = num[i][j] / den[i][j];  // exact IEEE div
  __syncthreads();

  // Parallel reduction + argmax: tid -> (tile = tid>>4, 6-ref slice)
  {
    const int tile = tid >> 4, rt = tid & 15, rr = rt * 6;
    const float dt = densT[tile];
    float best = -1e30f; int bi = 0;
#pragma unroll
    for (int j = 0; j < 6; ++j) {
      const int r = rr + j;
      if (r < 95) {
        float s = 0.f;
#pragma unroll
        for (int g = 0; g < 8; ++g) s += sbuf[(g * 32 + tile) * 97 + r];
        s = s * (1.0f / 96.0f) - 3.0f * fabsf(dt - densR[r]);
        if (s > best) { best = s; bi = r; }   // strict >: keeps lowest r
      }
    }
#pragma unroll
    for (int m = 8; m >= 1; m >>= 1) {
      const float ob = __shfl_xor(best, m, 64);
      const int oi = __shfl_xor(bi, m, 64);
      if (ob > best || (ob == best && oi < bi)) { best = ob; bi = oi; }
    }
    if (rt == 0) out[row0 * 128 + c0 + tile] = bi;
  }
}

// ---------------- Host launch ----------------
extern "C" void kernel_launch(void* const* d_in, const int* in_sizes, int n_in,
                              void* d_out, int out_size, void* d_ws, size_t ws_size,
                              hipStream_t stream) {
  (void)in_sizes; (void)n_in; (void)out_size; (void)ws_size;
  const float* img = (const float*)d_in[0];
  const float* chars = (const float*)d_in[1];
  int* out = (int*)d_out;
  float* refdata = (float*)d_ws;               // 96*12*96 floats = 442 KB
  float* densR = refdata + 96 * 12 * 96;       // +96 floats

  KF kf;
  {
    float gg[3], s = 0.f;
    for (int i = 0; i < 3; ++i) {
      const float c = (float)i - 1.0f;
      gg[i] = expf(-(c * c) / (2.0f * 1.5f * 1.5f));
      s += gg[i];
    }
    float gn[3];
    for (int i = 0; i < 3; ++i) gn[i] = gg[i] / s;
    float k2[9]; float ks = 0.f;
    for (int i = 0; i < 3; ++i)
      for (int j = 0; j < 3; ++j) { k2[i * 3 + j] = gn[i] * gn[j]; ks += k2[i * 3 + j]; }
    for (int k = 0; k < 9; ++k) kf.k[k] = k2[k] / ks;
  }

  hipLaunchKernelGGL(refprep_kernel, dim3(96), dim3(128), 0, stream,
                     chars, refdata, densR, kf);
  hipLaunchKernelGGL(ssim_main_kernel, dim3(256), dim3(512), 0, stream,
                     img, refdata, densR, out, kf);
}